// Round 2
// baseline (96.738 us; speedup 1.0000x reference)
//
#include <hip/hip_runtime.h>
#include <math.h>

// Tropical (max-plus) matmul: out[b,o] = max_k ( x[b,k] + W[o,k] )
// x: (2048,512) f32, W: (512,512) f32, out: (2048,512) f32.
//
// R1 post-mortem: 4x4 reg tile is LDS-pipe-bound (2 B read / elem-op -> ~20us
// floor; VALUBusy 46%). Fix: 8x8 reg tile (1 B/elem), 128x128 block tile.
// Only 64 tiles exist -> split-K=4 for 256 blocks (1/CU). Partials in ws +
// max-reduce kernel; CAS-max fallback if ws too small. All LDS access
// patterns 2-way/broadcast (free on gfx950, m136).

typedef float f2v __attribute__((ext_vector_type(2)));

#define B_ROWS 2048
#define K_DIM  512
#define O_DIM  512
#define BM 128
#define BN 128
#define BK 32
#define SPLITK 4
#define KRANGE (K_DIM / SPLITK)   // 128
#define KT     (KRANGE / BK)      // 4 tiles per block
#define LSTR   (BM + 4)           // 132 floats: bank = (4k + r) % 32

__device__ __forceinline__ void atomic_max_f32(float* p, float v) {
    unsigned int* up = (unsigned int*)p;
    unsigned int cur = *(volatile unsigned int*)up;
    while (__uint_as_float(cur) < v) {
        unsigned int assumed = cur;
        cur = atomicCAS(up, assumed, __float_as_uint(v));
        if (cur == assumed) break;
    }
}

template <bool USE_WS>
__global__ __launch_bounds__(256, 1) void tropical_main(
    const float* __restrict__ x, const float* __restrict__ W,
    float* __restrict__ dst)  // USE_WS: ws partials base; else d_out
{
    __shared__ float xs[BK][LSTR];
    __shared__ float wt[BK][LSTR];

    const int t  = threadIdx.x;
    const int bx = blockIdx.x;
    const int bn = (bx & 3) * BN;          // 4 N-tiles
    const int bm = ((bx >> 2) & 15) * BM;  // 16 M-tiles
    const int ks = bx >> 6;                // 4 K-splits
    const int k0 = ks * KRANGE;

    // Staging: thread t loads 16 contiguous floats of one row.
    // Consecutive lanes -> consecutive rows => transposed b32 LDS writes are
    // 2-way bank aliased (free). Global reads are 64B/lane, L2-resident.
    const int sr  = t & 127;          // row within tile
    const int skh = (t >> 7) * 16;    // k-offset 0 or 16

    // Compute: 16x16 thread grid, 8x8 = (4+4)x(4+4) register tile, halves
    // 64 apart so B-frag b128 reads land on distinct bank-quads (2-way).
    const int tx = t & 15;
    const int ty = t >> 4;
    const int c0 = tx * 4, c1 = 64 + tx * 4;
    const int r0 = ty * 4, r1 = 64 + ty * 4;

    float acc[2][4][2][4];  // [ri][i][ci][j]
#pragma unroll
    for (int ri = 0; ri < 2; ++ri)
#pragma unroll
        for (int i = 0; i < 4; ++i)
#pragma unroll
            for (int ci = 0; ci < 2; ++ci)
#pragma unroll
                for (int j = 0; j < 4; ++j) acc[ri][i][ci][j] = -INFINITY;

    const float* xb = x + (size_t)(bm + sr) * K_DIM + k0 + skh;
    const float* wb = W + (size_t)(bn + sr) * K_DIM + k0 + skh;

    float4 px[4], pw[4];
#pragma unroll
    for (int q = 0; q < 4; ++q) {
        px[q] = *(const float4*)(xb + 4 * q);
        pw[q] = *(const float4*)(wb + 4 * q);
    }

    for (int kt = 0; kt < KT; ++kt) {
        // drain staged registers -> LDS (transposed, k-major)
#pragma unroll
        for (int q = 0; q < 4; ++q) {
            const float* fx = (const float*)&px[q];
            const float* fw = (const float*)&pw[q];
#pragma unroll
            for (int j = 0; j < 4; ++j) {
                xs[skh + 4 * q + j][sr] = fx[j];
                wt[skh + 4 * q + j][sr] = fw[j];
            }
        }
        __syncthreads();

        // prefetch next tile into registers (hidden under compute)
        if (kt + 1 < KT) {
            const float* xn = xb + (kt + 1) * BK;
            const float* wn = wb + (kt + 1) * BK;
#pragma unroll
            for (int q = 0; q < 4; ++q) {
                px[q] = *(const float4*)(xn + 4 * q);
                pw[q] = *(const float4*)(wn + 4 * q);
            }
        }

        // 32 k-steps, paired: v_pk_add_f32 (f2v add) + v_max3_f32
#pragma unroll
        for (int k = 0; k < BK; k += 2) {
            float Af[2][2][4], Bf[2][2][4];
            *(float4*)&Af[0][0][0] = *(const float4*)&xs[k][r0];
            *(float4*)&Af[0][1][0] = *(const float4*)&xs[k + 1][r0];
            *(float4*)&Af[1][0][0] = *(const float4*)&xs[k][r1];
            *(float4*)&Af[1][1][0] = *(const float4*)&xs[k + 1][r1];
            *(float4*)&Bf[0][0][0] = *(const float4*)&wt[k][c0];
            *(float4*)&Bf[0][1][0] = *(const float4*)&wt[k + 1][c0];
            *(float4*)&Bf[1][0][0] = *(const float4*)&wt[k][c1];
            *(float4*)&Bf[1][1][0] = *(const float4*)&wt[k + 1][c1];
#pragma unroll
            for (int ri = 0; ri < 2; ++ri)
#pragma unroll
                for (int i = 0; i < 4; ++i)
#pragma unroll
                    for (int ci = 0; ci < 2; ++ci)
#pragma unroll
                        for (int j = 0; j < 4; ++j) {
                            f2v a = {Af[ri][0][i], Af[ri][1][i]};
                            f2v b = {Bf[ci][0][j], Bf[ci][1][j]};
                            f2v s = a + b;
                            acc[ri][i][ci][j] =
                                fmaxf(acc[ri][i][ci][j], fmaxf(s.x, s.y));
                        }
        }
        __syncthreads();
    }

    // epilogue
    if (USE_WS) {
        float* outp = dst + (size_t)ks * (B_ROWS * O_DIM);
#pragma unroll
        for (int ri = 0; ri < 2; ++ri) {
            const int rb = bm + (ri ? r1 : r0);
#pragma unroll
            for (int i = 0; i < 4; ++i) {
                float4 v0, v1;
                v0.x = acc[ri][i][0][0]; v0.y = acc[ri][i][0][1];
                v0.z = acc[ri][i][0][2]; v0.w = acc[ri][i][0][3];
                v1.x = acc[ri][i][1][0]; v1.y = acc[ri][i][1][1];
                v1.z = acc[ri][i][1][2]; v1.w = acc[ri][i][1][3];
                *(float4*)(outp + (size_t)(rb + i) * O_DIM + bn + c0) = v0;
                *(float4*)(outp + (size_t)(rb + i) * O_DIM + bn + c1) = v1;
            }
        }
    } else {
#pragma unroll
        for (int ri = 0; ri < 2; ++ri) {
            const int rb = bm + (ri ? r1 : r0);
#pragma unroll
            for (int i = 0; i < 4; ++i)
#pragma unroll
                for (int ci = 0; ci < 2; ++ci)
#pragma unroll
                    for (int j = 0; j < 4; ++j) {
                        const int gc = bn + (ci ? c1 : c0) + j;
                        atomic_max_f32(dst + (size_t)(rb + i) * O_DIM + gc,
                                       acc[ri][i][ci][j]);
                    }
        }
    }
}

__global__ __launch_bounds__(256) void tropical_reduce(
    const float4* __restrict__ ws, float4* __restrict__ out)
{
    const int i = blockIdx.x * 256 + threadIdx.x;   // 0..262143
    const int Q = B_ROWS * O_DIM / 4;               // 262144
    float4 a = ws[i], b = ws[i + Q], c = ws[i + 2 * Q], d = ws[i + 3 * Q];
    float4 r;
    r.x = fmaxf(fmaxf(a.x, b.x), fmaxf(c.x, d.x));
    r.y = fmaxf(fmaxf(a.y, b.y), fmaxf(c.y, d.y));
    r.z = fmaxf(fmaxf(a.z, b.z), fmaxf(c.z, d.z));
    r.w = fmaxf(fmaxf(a.w, b.w), fmaxf(c.w, d.w));
    out[i] = r;
}

__global__ __launch_bounds__(256) void tropical_fill(float4* __restrict__ out)
{
    const int i = blockIdx.x * 256 + threadIdx.x;
    out[i] = make_float4(-INFINITY, -INFINITY, -INFINITY, -INFINITY);
}

extern "C" void kernel_launch(void* const* d_in, const int* in_sizes, int n_in,
                              void* d_out, int out_size, void* d_ws, size_t ws_size,
                              hipStream_t stream) {
    const float* x = (const float*)d_in[0];   // (2048, 512)
    const float* W = (const float*)d_in[1];   // (512, 512)
    float* out = (float*)d_out;               // (2048, 512)

    const size_t partial_bytes = (size_t)SPLITK * B_ROWS * O_DIM * sizeof(float);
    if (ws_size >= partial_bytes) {
        tropical_main<true><<<256, 256, 0, stream>>>(x, W, (float*)d_ws);
        tropical_reduce<<<(B_ROWS * O_DIM / 4) / 256, 256, 0, stream>>>(
            (const float4*)d_ws, (float4*)out);
    } else {
        tropical_fill<<<(B_ROWS * O_DIM / 4) / 256, 256, 0, stream>>>((float4*)out);
        tropical_main<false><<<256, 256, 0, stream>>>(x, W, out);
    }
}

// Round 3
// 92.936 us; speedup vs baseline: 1.0409x; 1.0409x over previous
//
#include <hip/hip_runtime.h>
#include <math.h>

// Tropical (max-plus) matmul: out[b,o] = max_k ( x[b,k] + W[o,k] )
// x: (2048,512) f32, W: (512,512) f32, out: (2048,512) f32.
//
// R2 post-mortem: 1 wave/SIMD -> all LDS/global latency exposed (main ~40us
// vs ~10us LDS-pipe floor). R3: split-K=8 (512 blocks, 2/CU, 2 waves/SIMD)
// + k-paired LDS layout (f2v[kp][row]) so fragments arrive pre-packed:
// inner op = v_pk_add_f32 + v_max3_f32, zero interleave movs.

typedef float f2v __attribute__((ext_vector_type(2)));
typedef float f4v __attribute__((ext_vector_type(4)));

#define B_ROWS 2048
#define K_DIM  512
#define O_DIM  512
#define BM 128
#define BN 128
#define BK 32
#define SPLITK 8
#define KRANGE (K_DIM / SPLITK)   // 64
#define KT     (KRANGE / BK)      // 2 tiles per block

__device__ __forceinline__ void atomic_max_f32(float* p, float v) {
    unsigned int* up = (unsigned int*)p;
    unsigned int cur = *(volatile unsigned int*)up;
    while (__uint_as_float(cur) < v) {
        unsigned int assumed = cur;
        cur = atomicCAS(up, assumed, __float_as_uint(v));
        if (cur == assumed) break;
    }
}

template <bool USE_WS>
__global__ __launch_bounds__(256, 2) void tropical_main(
    const float* __restrict__ x, const float* __restrict__ W,
    float* __restrict__ dst)  // USE_WS: ws partials base; else d_out
{
    // k-pair-major LDS: element [kp][r] = { v[2kp][r], v[2kp+1][r] }.
    // Staging writes: 64 lanes -> 512 contiguous bytes (min bank-cycles).
    // Compute reads: b128 = 2 rows' pairs, 16-B aligned.
    __shared__ f2v xs2[BK / 2][BM];   // 16 KB
    __shared__ f2v ws2[BK / 2][BN];   // 16 KB

    const int t  = threadIdx.x;
    const int bx = blockIdx.x;
    const int bn = (bx & 3) * BN;          // 4 N-tiles
    const int bm = ((bx >> 2) & 15) * BM;  // 16 M-tiles
    const int ks = bx >> 6;                // 8 K-splits
    const int k0 = ks * KRANGE;

    // Staging: thread t covers 16 consecutive k of one row (4x float4).
    const int sr = t & 127;           // row within tile
    const int kh = t >> 7;            // 0/1 -> k-offset 16*kh, kp-offset 8*kh

    // Compute: 16x16 thread grid, 8x8 register tile as (4+4)x(4+4).
    const int tx = t & 15;
    const int ty = t >> 4;
    const int c0 = tx * 4, c1 = 64 + tx * 4;
    const int r0 = ty * 4, r1 = 64 + ty * 4;

    float acc[2][4][2][4];  // [ri][i][ci][j]
#pragma unroll
    for (int ri = 0; ri < 2; ++ri)
#pragma unroll
        for (int i = 0; i < 4; ++i)
#pragma unroll
            for (int ci = 0; ci < 2; ++ci)
#pragma unroll
                for (int j = 0; j < 4; ++j) acc[ri][i][ci][j] = -INFINITY;

    const float* xb = x + (size_t)(bm + sr) * K_DIM + k0 + 16 * kh;
    const float* wb = W + (size_t)(bn + sr) * K_DIM + k0 + 16 * kh;

    float4 px[4], pw[4];
#pragma unroll
    for (int q = 0; q < 4; ++q) {
        px[q] = *(const float4*)(xb + 4 * q);
        pw[q] = *(const float4*)(wb + 4 * q);
    }

    for (int kt = 0; kt < KT; ++kt) {
        // drain staged registers -> LDS, k-paired
#pragma unroll
        for (int q = 0; q < 4; ++q) {
            const int kp = 8 * kh + 2 * q;
            xs2[kp][sr]     = (f2v){px[q].x, px[q].y};
            xs2[kp + 1][sr] = (f2v){px[q].z, px[q].w};
            ws2[kp][sr]     = (f2v){pw[q].x, pw[q].y};
            ws2[kp + 1][sr] = (f2v){pw[q].z, pw[q].w};
        }
        __syncthreads();

        // prefetch next tile (hidden under compute below)
        if (kt + 1 < KT) {
            const float* xn = xb + (kt + 1) * BK;
            const float* wn = wb + (kt + 1) * BK;
#pragma unroll
            for (int q = 0; q < 4; ++q) {
                px[q] = *(const float4*)(xn + 4 * q);
                pw[q] = *(const float4*)(wn + 4 * q);
            }
        }

        // 16 k-pairs per tile: 8 b128 reads + 64 x (v_pk_add_f32 + v_max3_f32)
#pragma unroll
        for (int kp = 0; kp < BK / 2; ++kp) {
            f4v A[2][2], B[2][2];
            A[0][0] = *(const f4v*)&xs2[kp][r0];
            A[0][1] = *(const f4v*)&xs2[kp][r0 + 2];
            A[1][0] = *(const f4v*)&xs2[kp][r1];
            A[1][1] = *(const f4v*)&xs2[kp][r1 + 2];
            B[0][0] = *(const f4v*)&ws2[kp][c0];
            B[0][1] = *(const f4v*)&ws2[kp][c0 + 2];
            B[1][0] = *(const f4v*)&ws2[kp][c1];
            B[1][1] = *(const f4v*)&ws2[kp][c1 + 2];

            f2v a2[2][4], b2[2][4];
#pragma unroll
            for (int h = 0; h < 2; ++h) {
                a2[h][0] = A[h][0].xy; a2[h][1] = A[h][0].zw;
                a2[h][2] = A[h][1].xy; a2[h][3] = A[h][1].zw;
                b2[h][0] = B[h][0].xy; b2[h][1] = B[h][0].zw;
                b2[h][2] = B[h][1].xy; b2[h][3] = B[h][1].zw;
            }
#pragma unroll
            for (int ri = 0; ri < 2; ++ri)
#pragma unroll
                for (int i = 0; i < 4; ++i)
#pragma unroll
                    for (int ci = 0; ci < 2; ++ci)
#pragma unroll
                        for (int j = 0; j < 4; ++j) {
                            f2v s = a2[ri][i] + b2[ci][j];      // v_pk_add_f32
                            acc[ri][i][ci][j] =
                                fmaxf(acc[ri][i][ci][j],
                                      fmaxf(s.x, s.y));         // v_max3_f32
                        }
        }
        __syncthreads();
    }

    // epilogue
    if (USE_WS) {
        float* outp = dst + (size_t)ks * (B_ROWS * O_DIM);
#pragma unroll
        for (int ri = 0; ri < 2; ++ri) {
            const int rb = bm + (ri ? r1 : r0);
#pragma unroll
            for (int i = 0; i < 4; ++i) {
                float4 v0, v1;
                v0.x = acc[ri][i][0][0]; v0.y = acc[ri][i][0][1];
                v0.z = acc[ri][i][0][2]; v0.w = acc[ri][i][0][3];
                v1.x = acc[ri][i][1][0]; v1.y = acc[ri][i][1][1];
                v1.z = acc[ri][i][1][2]; v1.w = acc[ri][i][1][3];
                *(float4*)(outp + (size_t)(rb + i) * O_DIM + bn + c0) = v0;
                *(float4*)(outp + (size_t)(rb + i) * O_DIM + bn + c1) = v1;
            }
        }
    } else {
#pragma unroll
        for (int ri = 0; ri < 2; ++ri) {
            const int rb = bm + (ri ? r1 : r0);
#pragma unroll
            for (int i = 0; i < 4; ++i)
#pragma unroll
                for (int ci = 0; ci < 2; ++ci)
#pragma unroll
                    for (int j = 0; j < 4; ++j) {
                        const int gc = bn + (ci ? c1 : c0) + j;
                        atomic_max_f32(dst + (size_t)(rb + i) * O_DIM + gc,
                                       acc[ri][i][ci][j]);
                    }
        }
    }
}

__global__ __launch_bounds__(256) void tropical_reduce(
    const float4* __restrict__ ws, float4* __restrict__ out)
{
    const int i = blockIdx.x * 256 + threadIdx.x;   // 0..262143
    const int Q = B_ROWS * O_DIM / 4;               // 262144
    float4 r = ws[i];
#pragma unroll
    for (int p = 1; p < SPLITK; ++p) {
        float4 v = ws[i + p * Q];
        r.x = fmaxf(r.x, v.x);
        r.y = fmaxf(r.y, v.y);
        r.z = fmaxf(r.z, v.z);
        r.w = fmaxf(r.w, v.w);
    }
    out[i] = r;
}

__global__ __launch_bounds__(256) void tropical_fill(float4* __restrict__ out)
{
    const int i = blockIdx.x * 256 + threadIdx.x;
    out[i] = make_float4(-INFINITY, -INFINITY, -INFINITY, -INFINITY);
}

extern "C" void kernel_launch(void* const* d_in, const int* in_sizes, int n_in,
                              void* d_out, int out_size, void* d_ws, size_t ws_size,
                              hipStream_t stream) {
    const float* x = (const float*)d_in[0];   // (2048, 512)
    const float* W = (const float*)d_in[1];   // (512, 512)
    float* out = (float*)d_out;               // (2048, 512)

    const size_t partial_bytes = (size_t)SPLITK * B_ROWS * O_DIM * sizeof(float);
    const int nblocks = 16 * 4 * SPLITK;      // 512
    if (ws_size >= partial_bytes) {
        tropical_main<true><<<nblocks, 256, 0, stream>>>(x, W, (float*)d_ws);
        tropical_reduce<<<(B_ROWS * O_DIM / 4) / 256, 256, 0, stream>>>(
            (const float4*)d_ws, (float4*)out);
    } else {
        tropical_fill<<<(B_ROWS * O_DIM / 4) / 256, 256, 0, stream>>>((float4*)out);
        tropical_main<false><<<nblocks, 256, 0, stream>>>(x, W, out);
    }
}